// Round 15
// baseline (1106.185 us; speedup 1.0000x reference)
//
#include <hip/hip_runtime.h>
#include <hip/hip_cooperative_groups.h>
#include <math.h>

namespace cg = cooperative_groups;

#define BSZ 4
#define Lseq 2048
#define DM 64
#define ED 128
#define NST 32
#define DCONVK 16
#define NLAYERS 4
#define DTRANK 4
#define EPSV 1e-5f
#define NC 128                // chunks along L; block (b,c) owns one chunk
#define TT 16                 // tokens per chunk

__device__ __forceinline__ float sigf(float x) { return 1.0f / (1.0f + __expf(-x)); }
__device__ __forceinline__ float hsum4(float4 a) { return (a.x + a.y) + (a.z + a.w); }

struct Params {
    const float *x, *in_w, *in_b, *conv_w, *conv_b, *xproj_w, *dtproj_w, *dtproj_b;
    const float *A_log, *Dp, *outproj_w, *outproj_b, *norm_w, *fc_w, *fc_b;
    float *out, *xin, *zbuf, *aprod, *hloc, *hend;
};

// inproj: 64 -> 256 for 16 tokens; hn in LDS; writes xin (tid<128) / zbuf.
__device__ __forceinline__ void inproj16(
    const float* in_w_l, const float* in_b_l, const float (*hn)[DM],
    float* xin, float* zbuf, size_t t0, int tid)
{
    float4 w4[16];
    const float4* wr = (const float4*)(in_w_l + tid * DM);
    #pragma unroll
    for (int i = 0; i < 16; ++i) w4[i] = wr[i];
    const float bias = in_b_l[tid];
    #pragma unroll 2
    for (int tok = 0; tok < TT; ++tok) {
        const float4* hv4 = (const float4*)&hn[tok][0];
        float4 a4 = make_float4(0.f, 0.f, 0.f, 0.f);
        #pragma unroll
        for (int i = 0; i < 16; ++i) {
            float4 hv = hv4[i];
            a4.x = fmaf(hv.x, w4[i].x, a4.x);
            a4.y = fmaf(hv.y, w4[i].y, a4.y);
            a4.z = fmaf(hv.z, w4[i].z, a4.z);
            a4.w = fmaf(hv.w, w4[i].w, a4.w);
        }
        const float r = bias + hsum4(a4);
        if (tid < ED) xin[(t0 + tok) * ED + tid] = r;
        else          zbuf[(t0 + tok) * ED + (tid - ED)] = r;
    }
}

// ============ fused cooperative kernel: 512 blocks x 256, 28 KB LDS ============
__global__ __launch_bounds__(256) void k_mamba_fused(Params P)
{
    cg::grid_group grid = cg::this_grid();
    const int blk = blockIdx.x;            // BSZ*NC = 512
    const int b   = blk >> 7;
    const int c   = blk & 127;
    const int l0  = c * TT;
    const size_t t0 = (size_t)b * Lseq + l0;
    const int tid = threadIdx.x;
    const int e = tid & 127, half = tid >> 7;
    const int lane = tid & 63, wv = tid >> 6;
    const int e2 = tid >> 1, nh = tid & 1;   // pair-lane scan mapping

    __shared__ __align__(16) float smem[7168];   // 28 KB
    float (*xcs)[ED] = (float (*)[ED])smem;                  // [16][128]  8 KB
    float (*Bs)[NST] = (float (*)[NST])(smem + 2048);        // [16][32]   2 KB
    float (*Cs)[NST] = (float (*)[NST])(smem + 2560);        // [16][32]   2 KB
    float* uni = smem + 3072;                                // 16 KB union
    float* xs = uni;                                         // 3968 floats (A: conv stage)
    float (*dts)[DTRANK] = (float (*)[DTRANK])(uni + 3968);  // 64 floats  (A)
    float (*dl)[ED] = (float (*)[ED])uni;                    // [16][128]  (A tail + C)
    float (*ys)[ED] = (float (*)[ED])(uni + 2048);           // [16][128]  (C)
    float (*hn)[DM] = (float (*)[DM])(smem + 2048);          // [16][64] alias Bs+Cs
    float* sred = uni;                                       // head scratch

    float hres[4];   // residual h for tokens wv*4+j, d=lane — in registers

    // ========== pre-phase: layer-0 rmsnorm + inproj ==========
    {
        const float nw = P.norm_w[lane];
        #pragma unroll
        for (int j = 0; j < 4; ++j)
            hres[j] = P.x[(size_t)(t0 + wv * 4 + j) * DM + lane];
        #pragma unroll
        for (int j = 0; j < 4; ++j) {
            float ss = hres[j] * hres[j];
            #pragma unroll
            for (int off = 32; off; off >>= 1) ss += __shfl_xor(ss, off, 64);
            const float sc = rsqrtf(ss * (1.0f / DM) + EPSV);
            hn[wv * 4 + j][lane] = hres[j] * sc * nw;
        }
        __syncthreads();
        inproj16(P.in_w, P.in_b, hn, P.xin, P.zbuf, t0, tid);
    }
    grid.sync();

    // ========== layer loop ==========
    #pragma unroll 1
    for (int i = 0; i < NLAYERS; ++i) {
        const float* conv_w_i = P.conv_w + (size_t)i * ED * DCONVK;
        const float* conv_b_i = P.conv_b + (size_t)i * ED;
        const float* xproj_i  = P.xproj_w + (size_t)i * (DTRANK + 2 * NST) * ED;
        const float* dtw_i    = P.dtproj_w + (size_t)i * ED * DTRANK;
        const float* dtb_i    = P.dtproj_b + (size_t)i * ED;
        const float* Alog_i   = P.A_log + (size_t)i * ED * NST;
        const float* Dp_i     = P.Dp + (size_t)i * ED;

        // ---- Phase A: conv + silu + xproj + dtproj + local scan ----
        {
            const int NV = (TT + DCONVK - 1) * ED / 4;   // 992
            for (int idx4 = tid; idx4 < NV; idx4 += 256) {
                const int row = idx4 >> 5;
                const int lrow = l0 - (DCONVK - 1) + row;
                float4 v = make_float4(0.f, 0.f, 0.f, 0.f);
                if (lrow >= 0)
                    v = ((const float4*)(P.xin + ((size_t)b * Lseq + lrow) * ED))[idx4 & 31];
                ((float4*)xs)[idx4] = v;
            }
        }
        __syncthreads();
        {   // conv + silu
            float w[DCONVK];
            {
                const float4* cw = (const float4*)(conv_w_i + e * DCONVK);
                #pragma unroll
                for (int q = 0; q < 4; ++q) {
                    float4 cc = cw[q];
                    w[q*4+0] = cc.x; w[q*4+1] = cc.y; w[q*4+2] = cc.z; w[q*4+3] = cc.w;
                }
            }
            const float cb = conv_b_i[e];
            #pragma unroll 2
            for (int j = 0; j < 8; ++j) {
                const int tok = half * 8 + j;
                float acc = cb;
                #pragma unroll
                for (int k = 0; k < DCONVK; ++k)
                    acc = fmaf(xs[(tok + k) * ED + e], w[k], acc);
                const float xcv = acc * sigf(acc);
                xcs[tok][e] = xcv;
            }
        }
        __syncthreads();   // xs dead
        {   // xproj: 4 passes of w4[8], acc[4]
            float4 acc[4];
            #pragma unroll
            for (int j = 0; j < 4; ++j) acc[j] = make_float4(0.f, 0.f, 0.f, 0.f);
            #pragma unroll 1
            for (int p = 0; p < 4; ++p) {
                float4 w4[8];
                const float4* wr = (const float4*)(xproj_i + lane * ED + p * 32);
                #pragma unroll
                for (int q = 0; q < 8; ++q) w4[q] = wr[q];
                #pragma unroll
                for (int j = 0; j < 4; ++j) {
                    const float4* yv = (const float4*)&xcs[wv * 4 + j][p * 32];
                    #pragma unroll
                    for (int q = 0; q < 8; ++q) {
                        float4 hv = yv[q];
                        acc[j].x = fmaf(hv.x, w4[q].x, acc[j].x);
                        acc[j].y = fmaf(hv.y, w4[q].y, acc[j].y);
                        acc[j].z = fmaf(hv.z, w4[q].z, acc[j].z);
                        acc[j].w = fmaf(hv.w, w4[q].w, acc[j].w);
                    }
                }
            }
            #pragma unroll
            for (int j = 0; j < 4; ++j) {
                const int tok = wv * 4 + j;
                const float v = hsum4(acc[j]);
                if (lane < DTRANK)            dts[tok][lane] = v;
                else if (lane < DTRANK + NST) Bs[tok][lane - DTRANK] = v;
                else                          Cs[tok][lane - DTRANK - NST] = v;
            }
            {   // leftover rows 64..67 -> C idx 28..31
                const int ridx = lane & 3;
                const int ks   = (lane >> 2) & 3;
                const int tsub = lane >> 4;
                const int r4   = 64 + ridx;
                const int tok  = wv * 4 + tsub;
                const float4* wr = (const float4*)(xproj_i + r4 * ED + ks * 32);
                const float4* yv = (const float4*)&xcs[tok][ks * 32];
                float4 a4 = make_float4(0.f, 0.f, 0.f, 0.f);
                #pragma unroll
                for (int q = 0; q < 8; ++q) {
                    float4 hv = yv[q]; float4 wv4 = wr[q];
                    a4.x = fmaf(hv.x, wv4.x, a4.x);
                    a4.y = fmaf(hv.y, wv4.y, a4.y);
                    a4.z = fmaf(hv.z, wv4.z, a4.z);
                    a4.w = fmaf(hv.w, wv4.w, a4.w);
                }
                float v = hsum4(a4);
                v += __shfl_xor(v, 4, 64);
                v += __shfl_xor(v, 8, 64);
                if (ks == 0) Cs[tok][r4 - DTRANK - NST] = v;
            }
        }
        __syncthreads();
        {   // dtproj + softplus -> dl (aliases dead xs region)
            const float4 dwv = *(const float4*)(dtw_i + e * DTRANK);
            const float bias = dtb_i[e];
            #pragma unroll 2
            for (int j = 0; j < 8; ++j) {
                const int tok = half * 8 + j;
                float a = bias;
                a = fmaf(dts[tok][0], dwv.x, a);
                a = fmaf(dts[tok][1], dwv.y, a);
                a = fmaf(dts[tok][2], dwv.z, a);
                a = fmaf(dts[tok][3], dwv.w, a);
                dl[tok][e] = fmaxf(a, 0.f) + log1pf(__expf(-fabsf(a)));
            }
        }
        __syncthreads();
        {   // local scan: pair-lane mapping, two 8-state passes -> aprod/hloc
            float dsum = 0.f;
            #pragma unroll 4
            for (int l = 0; l < TT; ++l) dsum += dl[l][e2];
            #pragma unroll 1
            for (int g = 0; g < 2; ++g) {
                const int n0 = nh * 16 + g * 8;
                float Aen[8];
                {
                    const float4* a4 = (const float4*)(Alog_i + e2 * NST + n0);
                    const float4 v0 = a4[0], v1 = a4[1];
                    Aen[0] = -__expf(v0.x); Aen[1] = -__expf(v0.y);
                    Aen[2] = -__expf(v0.z); Aen[3] = -__expf(v0.w);
                    Aen[4] = -__expf(v1.x); Aen[5] = -__expf(v1.y);
                    Aen[6] = -__expf(v1.z); Aen[7] = -__expf(v1.w);
                }
                float hs[8];
                #pragma unroll
                for (int k = 0; k < 8; ++k) hs[k] = 0.f;
                #pragma unroll 2
                for (int l = 0; l < TT; ++l) {
                    const float de   = dl[l][e2];
                    const float dexc = de * xcs[l][e2];
                    const float4 B0 = *(const float4*)&Bs[l][n0];
                    const float4 B1 = *(const float4*)&Bs[l][n0 + 4];
                    float a;
                    a = __expf(de * Aen[0]); hs[0] = fmaf(a, hs[0], B0.x * dexc);
                    a = __expf(de * Aen[1]); hs[1] = fmaf(a, hs[1], B0.y * dexc);
                    a = __expf(de * Aen[2]); hs[2] = fmaf(a, hs[2], B0.z * dexc);
                    a = __expf(de * Aen[3]); hs[3] = fmaf(a, hs[3], B0.w * dexc);
                    a = __expf(de * Aen[4]); hs[4] = fmaf(a, hs[4], B1.x * dexc);
                    a = __expf(de * Aen[5]); hs[5] = fmaf(a, hs[5], B1.y * dexc);
                    a = __expf(de * Aen[6]); hs[6] = fmaf(a, hs[6], B1.z * dexc);
                    a = __expf(de * Aen[7]); hs[7] = fmaf(a, hs[7], B1.w * dexc);
                }
                const size_t idx = (((size_t)b * NC + c) * ED + e2) * NST + n0;
                *(float4*)(P.hloc + idx)     = make_float4(hs[0], hs[1], hs[2], hs[3]);
                *(float4*)(P.hloc + idx + 4) = make_float4(hs[4], hs[5], hs[6], hs[7]);
                *(float4*)(P.aprod + idx) =
                    make_float4(__expf(Aen[0] * dsum), __expf(Aen[1] * dsum),
                                __expf(Aen[2] * dsum), __expf(Aen[3] * dsum));
                *(float4*)(P.aprod + idx + 4) =
                    make_float4(__expf(Aen[4] * dsum), __expf(Aen[5] * dsum),
                                __expf(Aen[6] * dsum), __expf(Aen[7] * dsum));
            }
        }
        grid.sync();

        // ---- Phase B: chunk combine (first 64 blocks) ----
        if (blk < (BSZ * ED * NST) / 256) {
            const int gtid = blk * 256 + tid;
            const int bb = gtid >> 12;
            const int en = gtid & 4095;
            size_t idx = (size_t)bb * NC * (ED * NST) + en;
            float h = 0.f;
            #pragma unroll 4
            for (int cc = 0; cc < NC; ++cc) {
                const float a = P.aprod[idx];
                const float u = P.hloc[idx];
                P.hloc[idx] = h;
                h = fmaf(a, h, u);
                idx += ED * NST;
            }
            P.hend[(size_t)bb * (ED * NST) + en] = h;
        }
        grid.sync();

        if (i < NLAYERS - 1) {
            // ---- Phase C: rescan -> y -> outproj + residual + rms + inproj(i+1) ----
            #pragma unroll 1
            for (int g = 0; g < 2; ++g) {
                const int n0 = nh * 16 + g * 8;
                float Aen[8];
                {
                    const float4* a4 = (const float4*)(Alog_i + e2 * NST + n0);
                    const float4 v0 = a4[0], v1 = a4[1];
                    Aen[0] = -__expf(v0.x); Aen[1] = -__expf(v0.y);
                    Aen[2] = -__expf(v0.z); Aen[3] = -__expf(v0.w);
                    Aen[4] = -__expf(v1.x); Aen[5] = -__expf(v1.y);
                    Aen[6] = -__expf(v1.z); Aen[7] = -__expf(v1.w);
                }
                float hs[8];
                {
                    const size_t idx = (((size_t)b * NC + c) * ED + e2) * NST + n0;
                    const float4 h0 = *(const float4*)(P.hloc + idx);
                    const float4 h1 = *(const float4*)(P.hloc + idx + 4);
                    hs[0] = h0.x; hs[1] = h0.y; hs[2] = h0.z; hs[3] = h0.w;
                    hs[4] = h1.x; hs[5] = h1.y; hs[6] = h1.z; hs[7] = h1.w;
                }
                #pragma unroll 2
                for (int l = 0; l < TT; ++l) {
                    const float de   = dl[l][e2];
                    const float dexc = de * xcs[l][e2];
                    const float4 B0 = *(const float4*)&Bs[l][n0];
                    const float4 B1 = *(const float4*)&Bs[l][n0 + 4];
                    const float4 C0 = *(const float4*)&Cs[l][n0];
                    const float4 C1 = *(const float4*)&Cs[l][n0 + 4];
                    float a, p = 0.f;
                    a = __expf(de * Aen[0]); hs[0] = fmaf(a, hs[0], B0.x * dexc); p = fmaf(hs[0], C0.x, p);
                    a = __expf(de * Aen[1]); hs[1] = fmaf(a, hs[1], B0.y * dexc); p = fmaf(hs[1], C0.y, p);
                    a = __expf(de * Aen[2]); hs[2] = fmaf(a, hs[2], B0.z * dexc); p = fmaf(hs[2], C0.z, p);
                    a = __expf(de * Aen[3]); hs[3] = fmaf(a, hs[3], B0.w * dexc); p = fmaf(hs[3], C0.w, p);
                    a = __expf(de * Aen[4]); hs[4] = fmaf(a, hs[4], B1.x * dexc); p = fmaf(hs[4], C1.x, p);
                    a = __expf(de * Aen[5]); hs[5] = fmaf(a, hs[5], B1.y * dexc); p = fmaf(hs[5], C1.y, p);
                    a = __expf(de * Aen[6]); hs[6] = fmaf(a, hs[6], B1.z * dexc); p = fmaf(hs[6], C1.z, p);
                    a = __expf(de * Aen[7]); hs[7] = fmaf(a, hs[7], B1.w * dexc); p = fmaf(hs[7], C1.w, p);
                    const float pt = p + __shfl_xor(p, 1, 64);   // combine n-halves
                    if (nh == 0) {
                        if (g == 0) ys[l][e2] = pt;
                        else        ys[l][e2] += pt;
                    }
                }
            }
            __syncthreads();
            {   // finalize y: add skip + silu(z) gate
                const float dpe = Dp_i[e];
                #pragma unroll 2
                for (int j = 0; j < 8; ++j) {
                    const int tl = half * 8 + j;
                    const float zi = P.zbuf[(t0 + tl) * ED + e];
                    ys[tl][e] = (ys[tl][e] + dpe * xcs[tl][e]) * (zi * sigf(zi));
                }
            }
            __syncthreads();
            // outproj + residual(reg) + rms -> hn (aliases dead Bs/Cs)
            const float* ow = P.outproj_w + (size_t)i * DM * ED;
            const float nw = P.norm_w[(size_t)(i + 1) * DM + lane];
            {
                float4 acc[4];
                #pragma unroll
                for (int j = 0; j < 4; ++j) acc[j] = make_float4(0.f, 0.f, 0.f, 0.f);
                #pragma unroll 1
                for (int p = 0; p < 4; ++p) {
                    float4 w4[8];
                    const float4* wr = (const float4*)(ow + lane * ED + p * 32);
                    #pragma unroll
                    for (int q = 0; q < 8; ++q) w4[q] = wr[q];
                    #pragma unroll
                    for (int j = 0; j < 4; ++j) {
                        const float4* yv = (const float4*)&ys[wv * 4 + j][p * 32];
                        #pragma unroll
                        for (int q = 0; q < 8; ++q) {
                            float4 hv = yv[q];
                            acc[j].x = fmaf(hv.x, w4[q].x, acc[j].x);
                            acc[j].y = fmaf(hv.y, w4[q].y, acc[j].y);
                            acc[j].z = fmaf(hv.z, w4[q].z, acc[j].z);
                            acc[j].w = fmaf(hv.w, w4[q].w, acc[j].w);
                        }
                    }
                }
                const float obd = P.outproj_b[(size_t)i * DM + lane];
                #pragma unroll
                for (int j = 0; j < 4; ++j)
                    hres[j] = hsum4(acc[j]) + obd + hres[j];
            }
            __syncthreads();   // ys/Bs/Cs dead; hn region free
            #pragma unroll
            for (int j = 0; j < 4; ++j) {
                float ss = hres[j] * hres[j];
                #pragma unroll
                for (int off = 32; off; off >>= 1) ss += __shfl_xor(ss, off, 64);
                const float sc = rsqrtf(ss * (1.0f / DM) + EPSV);
                hn[wv * 4 + j][lane] = hres[j] * sc * nw;
            }
            __syncthreads();
            inproj16(P.in_w + (size_t)(i + 1) * 2 * ED * DM,
                     P.in_b + (size_t)(i + 1) * 2 * ED,
                     (const float (*)[DM])hn, P.xin, P.zbuf, t0, tid);
            grid.sync();   // next layer's conv halo needs all xin writes
        } else {
            // ---- last-layer head: block c == NC-1 holds token L-1 data ----
            if (c == NC - 1) {
                float val = 0.f;
                if (tid < ED) {
                    const float* hp = P.hend + (size_t)b * (ED * NST) + tid * NST;
                    float p = 0.f;
                    #pragma unroll
                    for (int n = 0; n < NST; ++n) p = fmaf(hp[n], Cs[TT - 1][n], p);
                    const float xce = xcs[TT - 1][tid];
                    const float zi  = P.zbuf[(t0 + TT - 1) * ED + tid];
                    val = (p + Dp_i[tid] * xce) * (zi * sigf(zi)) * P.fc_w[tid];
                }
                #pragma unroll
                for (int off = 32; off; off >>= 1) val += __shfl_xor(val, off, 64);
                if (lane == 0) sred[wv] = val;
                __syncthreads();
                if (tid == 0)
                    P.out[b] = sred[0] + sred[1] + sred[2] + sred[3] + P.fc_b[0];
            }
        }
    }
}

// ======================= R13 fallback kernels (verbatim) =======================
__global__ __launch_bounds__(256) void k_layer_gemm(
    const float* __restrict__ hin, const float* __restrict__ norm_w,
    const float* __restrict__ in_w, const float* __restrict__ in_b,
    float* __restrict__ xin, float* __restrict__ zb)
{
    const int t0 = blockIdx.x * TT;
    const int tid = threadIdx.x;
    const int lane = tid & 63;
    const int wv = tid >> 6;
    __shared__ __align__(16) float hn[TT][DM];

    const float nw = norm_w[lane];
    float hval[4];
    #pragma unroll
    for (int j = 0; j < 4; ++j)
        hval[j] = hin[(size_t)(t0 + wv * 4 + j) * DM + lane];

    #pragma unroll
    for (int j = 0; j < 4; ++j) {
        float ss = hval[j] * hval[j];
        #pragma unroll
        for (int off = 32; off; off >>= 1) ss += __shfl_xor(ss, off, 64);
        const float sc = rsqrtf(ss * (1.0f / DM) + EPSV);
        hn[wv * 4 + j][lane] = hval[j] * sc * nw;
    }
    __syncthreads();
    inproj16(in_w, in_b, (const float (*)[DM])hn, xin, zb, (size_t)t0, tid);
}

__global__ __launch_bounds__(256) void k_conv_scan(
    const float* __restrict__ xin, const float* __restrict__ conv_w,
    const float* __restrict__ conv_b, const float* __restrict__ xproj_w,
    const float* __restrict__ dtproj_w, const float* __restrict__ dtproj_b,
    const float* __restrict__ A_log,
    float* __restrict__ xc_out, float* __restrict__ delta_out,
    float* __restrict__ Bout, float* __restrict__ Cout,
    float* __restrict__ aprod, float* __restrict__ hloc)
{
    const int blk = blockIdx.x;
    const int b   = blk >> 7;
    const int c   = blk & 127;
    const int l0  = c * TT;
    const size_t t0 = (size_t)b * Lseq + l0;
    const int tid = threadIdx.x;
    __shared__ __align__(16) float xs[(TT + DCONVK - 1) * ED];
    __shared__ __align__(16) float xcs[TT][ED];
    __shared__ __align__(16) float Bs[TT][NST];
    __shared__ float dts[TT][DTRANK];
    float (*dl)[ED] = (float (*)[ED])xs;

    {
        const int NV = (TT + DCONVK - 1) * ED / 4;
        for (int idx4 = tid; idx4 < NV; idx4 += 256) {
            const int row = idx4 >> 5;
            const int lrow = l0 - (DCONVK - 1) + row;
            float4 v = make_float4(0.f, 0.f, 0.f, 0.f);
            if (lrow >= 0)
                v = ((const float4*)(xin + ((size_t)b * Lseq + lrow) * ED))[idx4 & 31];
            ((float4*)xs)[idx4] = v;
        }
    }
    __syncthreads();

    const int e = tid & 127, half = tid >> 7;
    {
        float w[DCONVK];
        {
            const float4* cw = (const float4*)(conv_w + e * DCONVK);
            #pragma unroll
            for (int i = 0; i < 4; ++i) {
                float4 cc = cw[i];
                w[i*4+0] = cc.x; w[i*4+1] = cc.y; w[i*4+2] = cc.z; w[i*4+3] = cc.w;
            }
        }
        const float cb = conv_b[e];
        #pragma unroll 2
        for (int j = 0; j < 8; ++j) {
            const int tok = half * 8 + j;
            float acc = cb;
            #pragma unroll
            for (int k = 0; k < DCONVK; ++k)
                acc = fmaf(xs[(tok + k) * ED + e], w[k], acc);
            const float xcv = acc * sigf(acc);
            xcs[tok][e] = xcv;
            xc_out[(t0 + tok) * ED + e] = xcv;
        }
    }
    __syncthreads();

    {
        const int wv = tid >> 6, lane = tid & 63;
        float4 acc[4];
        #pragma unroll
        for (int j = 0; j < 4; ++j) acc[j] = make_float4(0.f, 0.f, 0.f, 0.f);
        #pragma unroll 1
        for (int p = 0; p < 4; ++p) {
            float4 w4[8];
            const float4* wr = (const float4*)(xproj_w + lane * ED + p * 32);
            #pragma unroll
            for (int i = 0; i < 8; ++i) w4[i] = wr[i];
            #pragma unroll
            for (int j = 0; j < 4; ++j) {
                const float4* yv = (const float4*)&xcs[wv * 4 + j][p * 32];
                #pragma unroll
                for (int i = 0; i < 8; ++i) {
                    float4 hv = yv[i];
                    acc[j].x = fmaf(hv.x, w4[i].x, acc[j].x);
                    acc[j].y = fmaf(hv.y, w4[i].y, acc[j].y);
                    acc[j].z = fmaf(hv.z, w4[i].z, acc[j].z);
                    acc[j].w = fmaf(hv.w, w4[i].w, acc[j].w);
                }
            }
        }
        #pragma unroll
        for (int j = 0; j < 4; ++j) {
            const int tok = wv * 4 + j;
            const float v = hsum4(acc[j]);
            if (lane < DTRANK) {
                dts[tok][lane] = v;
            } else if (lane < DTRANK + NST) {
                Bs[tok][lane - DTRANK] = v;
                Bout[(t0 + tok) * NST + (lane - DTRANK)] = v;
            } else {
                Cout[(t0 + tok) * NST + (lane - DTRANK - NST)] = v;
            }
        }
        {
            const int ridx = lane & 3;
            const int ks   = (lane >> 2) & 3;
            const int tsub = lane >> 4;
            const int r4   = 64 + ridx;
            const int tok  = wv * 4 + tsub;
            const float4* wr = (const float4*)(xproj_w + r4 * ED + ks * 32);
            const float4* yv = (const float4*)&xcs[tok][ks * 32];
            float4 a4 = make_float4(0.f, 0.f, 0.f, 0.f);
            #pragma unroll
            for (int i = 0; i < 8; ++i) {
                float4 hv = yv[i]; float4 wv4 = wr[i];
                a4.x = fmaf(hv.x, wv4.x, a4.x);
                a4.y = fmaf(hv.y, wv4.y, a4.y);
                a4.z = fmaf(hv.z, wv4.z, a4.z);
                a4.w = fmaf(hv.w, wv4.w, a4.w);
            }
            float v = hsum4(a4);
            v += __shfl_xor(v, 4, 64);
            v += __shfl_xor(v, 8, 64);
            if (ks == 0) Cout[(t0 + tok) * NST + (r4 - DTRANK - NST)] = v;
        }
    }
    __syncthreads();

    {
        const float4 dwv = *(const float4*)(dtproj_w + e * DTRANK);
        const float bias = dtproj_b[e];
        #pragma unroll 2
        for (int j = 0; j < 8; ++j) {
            const int tok = half * 8 + j;
            float a = bias;
            a = fmaf(dts[tok][0], dwv.x, a);
            a = fmaf(dts[tok][1], dwv.y, a);
            a = fmaf(dts[tok][2], dwv.z, a);
            a = fmaf(dts[tok][3], dwv.w, a);
            const float sp = fmaxf(a, 0.f) + log1pf(__expf(-fabsf(a)));
            dl[tok][e] = sp;
            delta_out[(t0 + tok) * ED + e] = sp;
        }
    }
    __syncthreads();

    {
        float dsum = 0.f;
        #pragma unroll 4
        for (int l = 0; l < TT; ++l) dsum += dl[l][e];

        #pragma unroll 1
        for (int g = 0; g < 2; ++g) {
            const int n0 = half * 16 + g * 8;
            float Aen[8];
            {
                const float4* a4 = (const float4*)(A_log + e * NST + n0);
                const float4 v0 = a4[0], v1 = a4[1];
                Aen[0] = -__expf(v0.x); Aen[1] = -__expf(v0.y);
                Aen[2] = -__expf(v0.z); Aen[3] = -__expf(v0.w);
                Aen[4] = -__expf(v1.x); Aen[5] = -__expf(v1.y);
                Aen[6] = -__expf(v1.z); Aen[7] = -__expf(v1.w);
            }
            float hs[8];
            #pragma unroll
            for (int k = 0; k < 8; ++k) hs[k] = 0.f;
            #pragma unroll 2
            for (int l = 0; l < TT; ++l) {
                const float de   = dl[l][e];
                const float dexc = de * xcs[l][e];
                const float4 B0 = *(const float4*)&Bs[l][n0];
                const float4 B1 = *(const float4*)&Bs[l][n0 + 4];
                float a;
                a = __expf(de * Aen[0]); hs[0] = fmaf(a, hs[0], B0.x * dexc);
                a = __expf(de * Aen[1]); hs[1] = fmaf(a, hs[1], B0.y * dexc);
                a = __expf(de * Aen[2]); hs[2] = fmaf(a, hs[2], B0.z * dexc);
                a = __expf(de * Aen[3]); hs[3] = fmaf(a, hs[3], B0.w * dexc);
                a = __expf(de * Aen[4]); hs[4] = fmaf(a, hs[4], B1.x * dexc);
                a = __expf(de * Aen[5]); hs[5] = fmaf(a, hs[5], B1.y * dexc);
                a = __expf(de * Aen[6]); hs[6] = fmaf(a, hs[6], B1.z * dexc);
                a = __expf(de * Aen[7]); hs[7] = fmaf(a, hs[7], B1.w * dexc);
            }
            const size_t idx = (((size_t)b * NC + c) * ED + e) * NST + n0;
            *(float4*)(hloc + idx)     = make_float4(hs[0], hs[1], hs[2], hs[3]);
            *(float4*)(hloc + idx + 4) = make_float4(hs[4], hs[5], hs[6], hs[7]);
            *(float4*)(aprod + idx) =
                make_float4(__expf(Aen[0] * dsum), __expf(Aen[1] * dsum),
                            __expf(Aen[2] * dsum), __expf(Aen[3] * dsum));
            *(float4*)(aprod + idx + 4) =
                make_float4(__expf(Aen[4] * dsum), __expf(Aen[5] * dsum),
                            __expf(Aen[6] * dsum), __expf(Aen[7] * dsum));
        }
    }
}

__global__ __launch_bounds__(256) void k_scan_combine(
    const float* __restrict__ aprod, float* __restrict__ hloc,
    float* __restrict__ hend)
{
    const int tid = blockIdx.x * 256 + threadIdx.x;
    const int b = tid >> 12;
    const int en = tid & 4095;
    size_t idx = (size_t)b * NC * (ED * NST) + en;
    float h = 0.f;
    #pragma unroll 4
    for (int c = 0; c < NC; ++c) {
        const float a = aprod[idx];
        const float u = hloc[idx];
        hloc[idx] = h;
        h = fmaf(a, h, u);
        idx += ED * NST;
    }
    hend[(size_t)b * (ED * NST) + en] = h;
}

__global__ __launch_bounds__(256) void k_scan_gemm(
    const float* __restrict__ delta, const float* __restrict__ Bv,
    const float* __restrict__ Cv, const float* __restrict__ xc,
    const float* __restrict__ zbin, const float* __restrict__ A_log,
    const float* __restrict__ Dp, const float* __restrict__ hinit,
    const float* __restrict__ ow, const float* __restrict__ ob,
    const float* __restrict__ hin, const float* __restrict__ norm_w,
    const float* __restrict__ in_w, const float* __restrict__ in_b,
    float* __restrict__ hout, float* __restrict__ xin, float* __restrict__ zb)
{
    const int blk = blockIdx.x;
    const int b   = blk >> 7;
    const int c   = blk & 127;
    const int l0  = c * TT;
    const size_t t0 = (size_t)b * Lseq + l0;
    const int tid = threadIdx.x;
    const int e = tid & 127, half = tid >> 7;

    __shared__ __align__(16) float dlS[TT][ED];
    __shared__ __align__(16) float xcS[TT][ED];
    __shared__ __align__(16) float BsS[TT][NST];
    __shared__ __align__(16) float CsS[TT][NST];
    __shared__ __align__(16) float ys[TT][ED];
    __shared__ __align__(16) float pp[2][TT][ED];
    __shared__ __align__(16) float hn[TT][DM];

    {
        const float4* dsrc = (const float4*)(delta + t0 * ED);
        const float4* xsrc = (const float4*)(xc + t0 * ED);
        float4* ddst = (float4*)&dlS[0][0];
        float4* xdst = (float4*)&xcS[0][0];
        #pragma unroll
        for (int i = 0; i < 2; ++i) {
            ddst[tid + i * 256] = dsrc[tid + i * 256];
            xdst[tid + i * 256] = xsrc[tid + i * 256];
        }
        if (tid < 128) {
            ((float4*)&BsS[0][0])[tid] = ((const float4*)(Bv + t0 * NST))[tid];
            ((float4*)&CsS[0][0])[tid] = ((const float4*)(Cv + t0 * NST))[tid];
        }
    }
    __syncthreads();

    #pragma unroll 1
    for (int g = 0; g < 2; ++g) {
        const int n0 = half * 16 + g * 8;
        float Aen[8];
        {
            const float4* a4 = (const float4*)(A_log + e * NST + n0);
            const float4 v0 = a4[0], v1 = a4[1];
            Aen[0] = -__expf(v0.x); Aen[1] = -__expf(v0.y);
            Aen[2] = -__expf(v0.z); Aen[3] = -__expf(v0.w);
            Aen[4] = -__expf(v1.x); Aen[5] = -__expf(v1.y);
            Aen[6] = -__expf(v1.z); Aen[7] = -__expf(v1.w);
        }
        float hs[8];
        {
            const size_t idx = (((size_t)b * NC + c) * ED + e) * NST + n0;
            const float4 h0 = *(const float4*)(hinit + idx);
            const float4 h1 = *(const float4*)(hinit + idx + 4);
            hs[0] = h0.x; hs[1] = h0.y; hs[2] = h0.z; hs[3] = h0.w;
            hs[4] = h1.x; hs[5] = h1.y; hs[6] = h1.z; hs[7] = h1.w;
        }
        #pragma unroll 2
        for (int l = 0; l < TT; ++l) {
            const float de   = dlS[l][e];
            const float dexc = de * xcS[l][e];
            const float4 B0 = *(const float4*)&BsS[l][n0];
            const float4 B1 = *(const float4*)&BsS[l][n0 + 4];
            const float4 C0 = *(const float4*)&CsS[l][n0];
            const float4 C1 = *(const float4*)&CsS[l][n0 + 4];
            float a, p = 0.f;
            a = __expf(de * Aen[0]); hs[0] = fmaf(a, hs[0], B0.x * dexc); p = fmaf(hs[0], C0.x, p);
            a = __expf(de * Aen[1]); hs[1] = fmaf(a, hs[1], B0.y * dexc); p = fmaf(hs[1], C0.y, p);
            a = __expf(de * Aen[2]); hs[2] = fmaf(a, hs[2], B0.z * dexc); p = fmaf(hs[2], C0.z, p);
            a = __expf(de * Aen[3]); hs[3] = fmaf(a, hs[3], B0.w * dexc); p = fmaf(hs[3], C0.w, p);
            a = __expf(de * Aen[4]); hs[4] = fmaf(a, hs[4], B1.x * dexc); p = fmaf(hs[4], C1.x, p);
            a = __expf(de * Aen[5]); hs[5] = fmaf(a, hs[5], B1.y * dexc); p = fmaf(hs[5], C1.y, p);
            a = __expf(de * Aen[6]); hs[6] = fmaf(a, hs[6], B1.z * dexc); p = fmaf(hs[6], C1.z, p);
            a = __expf(de * Aen[7]); hs[7] = fmaf(a, hs[7], B1.w * dexc); p = fmaf(hs[7], C1.w, p);
            if (g == 0) pp[half][l][e] = p;
            else        pp[half][l][e] += p;
        }
    }
    __syncthreads();
    {
        const float dpe = Dp[e];
        #pragma unroll 2
        for (int j = 0; j < 8; ++j) {
            const int tl = half * 8 + j;
            const size_t tok = t0 + tl;
            const float p = pp[0][tl][e] + pp[1][tl][e];
            const float zi = zbin[tok * ED + e];
            ys[tl][e] = (p + dpe * xcS[tl][e]) * (zi * sigf(zi));
        }
    }
    __syncthreads();

    const int lane = tid & 63;
    const int wv = tid >> 6;
    const float nw = norm_w[lane];
    float hval[4];
    {
        float4 acc[4];
        #pragma unroll
        for (int j = 0; j < 4; ++j) acc[j] = make_float4(0.f, 0.f, 0.f, 0.f);
        #pragma unroll 1
        for (int p = 0; p < 4; ++p) {
            float4 w4[8];
            const float4* wr = (const float4*)(ow + lane * ED + p * 32);
            #pragma unroll
            for (int q = 0; q < 8; ++q) w4[q] = wr[q];
            #pragma unroll
            for (int j = 0; j < 4; ++j) {
                const float4* yv = (const float4*)&ys[wv * 4 + j][p * 32];
                #pragma unroll
                for (int q = 0; q < 8; ++q) {
                    float4 hv = yv[q];
                    acc[j].x = fmaf(hv.x, w4[q].x, acc[j].x);
                    acc[j].y = fmaf(hv.y, w4[q].y, acc[j].y);
                    acc[j].z = fmaf(hv.z, w4[q].z, acc[j].z);
                    acc[j].w = fmaf(hv.w, w4[q].w, acc[j].w);
                }
            }
        }
        const float obd = ob[lane];
        #pragma unroll
        for (int j = 0; j < 4; ++j) {
            const size_t tok = t0 + wv * 4 + j;
            hval[j] = hsum4(acc[j]) + obd + hin[tok * DM + lane];
            hout[tok * DM + lane] = hval[j];
        }
    }
    #pragma unroll
    for (int j = 0; j < 4; ++j) {
        float ss = hval[j] * hval[j];
        #pragma unroll
        for (int off = 32; off; off >>= 1) ss += __shfl_xor(ss, off, 64);
        const float sc = rsqrtf(ss * (1.0f / DM) + EPSV);
        hn[wv * 4 + j][lane] = hval[j] * sc * nw;
    }
    __syncthreads();
    inproj16(in_w, in_b, (const float (*)[DM])hn, xin, zb, t0, tid);
}

__global__ __launch_bounds__(128) void k_final_last(
    const float* __restrict__ hend, const float* __restrict__ Cv,
    const float* __restrict__ xc, const float* __restrict__ zb,
    const float* __restrict__ Dp, const float* __restrict__ fcw,
    const float* __restrict__ fcb, float* __restrict__ out)
{
    const int b = blockIdx.x;
    const int e = threadIdx.x;
    const size_t tok = (size_t)b * Lseq + (Lseq - 1);
    const float* hp = hend + (size_t)b * (ED * NST) + e * NST;
    const float* cp = Cv + tok * NST;
    float p = 0.f;
    #pragma unroll
    for (int n = 0; n < NST; ++n) p = fmaf(hp[n], cp[n], p);
    const float xce = xc[tok * ED + e];
    const float zi  = zb[tok * ED + e];
    float val = (p + Dp[e] * xce) * (zi * sigf(zi)) * fcw[e];
    __shared__ float sred[2];
    #pragma unroll
    for (int off = 32; off; off >>= 1) val += __shfl_xor(val, off, 64);
    if ((threadIdx.x & 63) == 0) sred[threadIdx.x >> 6] = val;
    __syncthreads();
    if (threadIdx.x == 0) out[b] = sred[0] + sred[1] + fcb[0];
}

extern "C" void kernel_launch(void* const* d_in, const int* in_sizes, int n_in,
                              void* d_out, int out_size, void* d_ws, size_t ws_size,
                              hipStream_t stream)
{
    const float* x         = (const float*)d_in[0];
    const float* in_w      = (const float*)d_in[1];
    const float* in_b      = (const float*)d_in[2];
    const float* conv_w    = (const float*)d_in[3];
    const float* conv_b    = (const float*)d_in[4];
    const float* xproj_w   = (const float*)d_in[5];
    const float* dtproj_w  = (const float*)d_in[6];
    const float* dtproj_b  = (const float*)d_in[7];
    const float* A_log     = (const float*)d_in[8];
    const float* Dp        = (const float*)d_in[9];
    const float* outproj_w = (const float*)d_in[10];
    const float* outproj_b = (const float*)d_in[11];
    const float* norm_w    = (const float*)d_in[12];
    const float* fc_w      = (const float*)d_in[13];
    const float* fc_b      = (const float*)d_in[14];

    const size_t TOK = (size_t)BSZ * Lseq;
    float* ws = (float*)d_ws;
    float* xin   = ws; ws += TOK * ED;                      // 4 MB
    float* zbuf  = ws; ws += TOK * ED;                      // 4 MB
    float* aprod = ws; ws += (size_t)BSZ * NC * ED * NST;   // 8 MB
    float* hloc  = ws; ws += (size_t)BSZ * NC * ED * NST;   // 8 MB
    float* hend  = ws; ws += (size_t)BSZ * ED * NST;
    // fallback-only scratch
    float* h0    = ws; ws += TOK * DM;
    float* h1    = ws; ws += TOK * DM;
    float* xc    = ws; ws += TOK * ED;
    float* dlt   = ws; ws += TOK * ED;
    float* Bv    = ws; ws += TOK * NST;
    float* Cv    = ws; ws += TOK * NST;

    Params P;
    P.x = x; P.in_w = in_w; P.in_b = in_b; P.conv_w = conv_w; P.conv_b = conv_b;
    P.xproj_w = xproj_w; P.dtproj_w = dtproj_w; P.dtproj_b = dtproj_b;
    P.A_log = A_log; P.Dp = Dp; P.outproj_w = outproj_w; P.outproj_b = outproj_b;
    P.norm_w = norm_w; P.fc_w = fc_w; P.fc_b = fc_b;
    P.out = (float*)d_out; P.xin = xin; P.zbuf = zbuf;
    P.aprod = aprod; P.hloc = hloc; P.hend = hend;

    void* args[] = { (void*)&P };
    hipError_t err = hipLaunchCooperativeKernel((const void*)k_mamba_fused,
                                                dim3(BSZ * NC), dim3(256),
                                                args, 0, stream);
    if (err != hipSuccess) {
        (void)hipGetLastError();   // clear sticky error; use R13 path
        const float* hres = x;
        float* hbufs[2] = { h0, h1 };
        k_layer_gemm<<<(int)(TOK / TT), 256, 0, stream>>>(
            x, norm_w, in_w, in_b, xin, zbuf);
        for (int i = 0; i < NLAYERS; ++i) {
            const int last = (i == NLAYERS - 1);
            const float* Alog_i = A_log + (size_t)i * ED * NST;
            k_conv_scan<<<(int)(BSZ * NC), 256, 0, stream>>>(
                xin, conv_w + (size_t)i * ED * DCONVK, conv_b + (size_t)i * ED,
                xproj_w + (size_t)i * (DTRANK + 2 * NST) * ED,
                dtproj_w + (size_t)i * ED * DTRANK, dtproj_b + (size_t)i * ED,
                Alog_i, xc, dlt, Bv, Cv, aprod, hloc);
            k_scan_combine<<<(BSZ * ED * NST) / 256, 256, 0, stream>>>(
                aprod, hloc, hend);
            if (!last) {
                float* hout = hbufs[i & 1];
                k_scan_gemm<<<(int)(BSZ * NC), 256, 0, stream>>>(
                    dlt, Bv, Cv, xc, zbuf, Alog_i, Dp + (size_t)i * ED, hloc,
                    outproj_w + (size_t)i * DM * ED, outproj_b + (size_t)i * DM,
                    hres, norm_w + (size_t)(i + 1) * DM,
                    in_w + (size_t)(i + 1) * 2 * ED * DM,
                    in_b + (size_t)(i + 1) * 2 * ED,
                    hout, xin, zbuf);
                hres = hout;
            } else {
                k_final_last<<<BSZ, 128, 0, stream>>>(
                    hend, Cv, xc, zbuf, Dp + (size_t)i * ED, fc_w, fc_b, (float*)d_out);
            }
        }
    }
}

// Round 16
// 375.547 us; speedup vs baseline: 2.9455x; 2.9455x over previous
//
#include <hip/hip_runtime.h>
#include <math.h>

#define BSZ 4
#define Lseq 2048
#define DM 64
#define ED 128
#define NST 32
#define DCONVK 16
#define NLAYERS 4
#define DTRANK 4
#define EPSV 1e-5f
#define NC 128                // chunks along L (chunk == conv tile == gemm tile)
#define TT 16                 // tokens per block

__device__ __forceinline__ float sigf(float x) { return 1.0f / (1.0f + __expf(-x)); }
__device__ __forceinline__ float hsum4(float4 a) { return (a.x + a.y) + (a.z + a.w); }

// inproj: 64 -> 256 for 16 tokens; hn in LDS; writes xin (tid<128) / zbuf.
__device__ __forceinline__ void inproj16(
    const float* in_w_l, const float* in_b_l, const float (*hn)[DM],
    float* xin, float* zbuf, size_t t0, int tid)
{
    float4 w4[16];
    const float4* wr = (const float4*)(in_w_l + tid * DM);
    #pragma unroll
    for (int i = 0; i < 16; ++i) w4[i] = wr[i];
    const float bias = in_b_l[tid];
    #pragma unroll 2
    for (int tok = 0; tok < TT; ++tok) {
        const float4* hv4 = (const float4*)&hn[tok][0];
        float4 a4 = make_float4(0.f, 0.f, 0.f, 0.f);
        #pragma unroll
        for (int i = 0; i < 16; ++i) {
            float4 hv = hv4[i];
            a4.x = fmaf(hv.x, w4[i].x, a4.x);
            a4.y = fmaf(hv.y, w4[i].y, a4.y);
            a4.z = fmaf(hv.z, w4[i].z, a4.z);
            a4.w = fmaf(hv.w, w4[i].w, a4.w);
        }
        const float r = bias + hsum4(a4);
        if (tid < ED) xin[(t0 + tok) * ED + tid] = r;
        else          zbuf[(t0 + tok) * ED + (tid - ED)] = r;
    }
}

// ---------------- K_A (layer 0 only): rmsnorm + inproj, 16 tokens/block
__global__ __launch_bounds__(256) void k_layer_gemm(
    const float* __restrict__ hin, const float* __restrict__ norm_w,
    const float* __restrict__ in_w, const float* __restrict__ in_b,
    float* __restrict__ xin, float* __restrict__ zb)
{
    const int t0 = blockIdx.x * TT;
    const int tid = threadIdx.x;
    const int lane = tid & 63;
    const int wv = tid >> 6;
    __shared__ __align__(16) float hn[TT][DM];

    const float nw = norm_w[lane];
    float hval[4];
    #pragma unroll
    for (int j = 0; j < 4; ++j)
        hval[j] = hin[(size_t)(t0 + wv * 4 + j) * DM + lane];

    #pragma unroll
    for (int j = 0; j < 4; ++j) {
        float ss = hval[j] * hval[j];
        #pragma unroll
        for (int off = 32; off; off >>= 1) ss += __shfl_xor(ss, off, 64);
        const float sc = rsqrtf(ss * (1.0f / DM) + EPSV);
        hn[wv * 4 + j][lane] = hval[j] * sc * nw;
    }
    __syncthreads();
    inproj16(in_w, in_b, (const float (*)[DM])hn, xin, zb, (size_t)t0, tid);
}

// ---------------- K_B: conv + silu + xproj + dtproj + local scan — 1 chunk/block
// Aen + conv weights hoisted to kernel entry so their global-load latency
// overlaps the LDS staging loop. All phase register shapes are R13's proven
// bounded tiles (unroll-2 token loops, 4x w4[8] weight passes, 2x 8-state scan).
__global__ __launch_bounds__(256) void k_conv_scan(
    const float* __restrict__ xin, const float* __restrict__ conv_w,
    const float* __restrict__ conv_b, const float* __restrict__ xproj_w,
    const float* __restrict__ dtproj_w, const float* __restrict__ dtproj_b,
    const float* __restrict__ A_log,
    float* __restrict__ xc_out, float* __restrict__ delta_out,
    float* __restrict__ Bout, float* __restrict__ Cout,
    float* __restrict__ aprod, float* __restrict__ hloc)
{
    const int blk = blockIdx.x;             // BSZ * NC = 512 blocks
    const int b   = blk >> 7;               // NC = 128
    const int c   = blk & 127;
    const int l0  = c * TT;
    const size_t t0 = (size_t)b * Lseq + l0;
    const int tid = threadIdx.x;
    const int e = tid & 127, half = tid >> 7;
    __shared__ __align__(16) float xs[(TT + DCONVK - 1) * ED];   // 31 rows, 15.5 KB
    __shared__ __align__(16) float xcs[TT][ED];                   // 8 KB
    __shared__ __align__(16) float Bs[TT][NST];                   // 2 KB
    __shared__ float dts[TT][DTRANK];
    float (*dl)[ED] = (float (*)[ED])xs;    // alias: xs dead after conv phase

    // ---- hoisted global loads (overlap with staging) ----
    float Aen16[16];
    {
        const float4* a4 = (const float4*)(A_log + e * NST + half * 16);
        #pragma unroll
        for (int i = 0; i < 4; ++i) {
            float4 v = a4[i];
            Aen16[i*4+0] = -__expf(v.x); Aen16[i*4+1] = -__expf(v.y);
            Aen16[i*4+2] = -__expf(v.z); Aen16[i*4+3] = -__expf(v.w);
        }
    }
    float w[DCONVK];
    {
        const float4* cw = (const float4*)(conv_w + e * DCONVK);
        #pragma unroll
        for (int i = 0; i < 4; ++i) {
            float4 cc = cw[i];
            w[i*4+0] = cc.x; w[i*4+1] = cc.y; w[i*4+2] = cc.z; w[i*4+3] = cc.w;
        }
    }
    const float cb = conv_b[e];

    {
        const int NV = (TT + DCONVK - 1) * ED / 4;   // 992
        for (int idx4 = tid; idx4 < NV; idx4 += 256) {
            const int row = idx4 >> 5;
            const int lrow = l0 - (DCONVK - 1) + row;
            float4 v = make_float4(0.f, 0.f, 0.f, 0.f);
            if (lrow >= 0)
                v = ((const float4*)(xin + ((size_t)b * Lseq + lrow) * ED))[idx4 & 31];
            ((float4*)xs)[idx4] = v;
        }
    }
    __syncthreads();

    {   // conv + silu
        #pragma unroll 2
        for (int j = 0; j < 8; ++j) {
            const int tok = half * 8 + j;
            float acc = cb;
            #pragma unroll
            for (int k = 0; k < DCONVK; ++k)
                acc = fmaf(xs[(tok + k) * ED + e], w[k], acc);
            const float xcv = acc * sigf(acc);
            xcs[tok][e] = xcv;
            xc_out[(t0 + tok) * ED + e] = xcv;
        }
    }
    __syncthreads();   // xs dead from here on

    {   // xproj: 4 passes of w4[8], acc[4]
        const int wv = tid >> 6, lane = tid & 63;
        float4 acc[4];
        #pragma unroll
        for (int j = 0; j < 4; ++j) acc[j] = make_float4(0.f, 0.f, 0.f, 0.f);
        #pragma unroll 1
        for (int p = 0; p < 4; ++p) {
            float4 w4[8];
            const float4* wr = (const float4*)(xproj_w + lane * ED + p * 32);
            #pragma unroll
            for (int i = 0; i < 8; ++i) w4[i] = wr[i];
            #pragma unroll
            for (int j = 0; j < 4; ++j) {
                const float4* yv = (const float4*)&xcs[wv * 4 + j][p * 32];
                #pragma unroll
                for (int i = 0; i < 8; ++i) {
                    float4 hv = yv[i];
                    acc[j].x = fmaf(hv.x, w4[i].x, acc[j].x);
                    acc[j].y = fmaf(hv.y, w4[i].y, acc[j].y);
                    acc[j].z = fmaf(hv.z, w4[i].z, acc[j].z);
                    acc[j].w = fmaf(hv.w, w4[i].w, acc[j].w);
                }
            }
        }
        #pragma unroll
        for (int j = 0; j < 4; ++j) {
            const int tok = wv * 4 + j;
            const float v = hsum4(acc[j]);
            if (lane < DTRANK) {
                dts[tok][lane] = v;
            } else if (lane < DTRANK + NST) {
                Bs[tok][lane - DTRANK] = v;
                Bout[(t0 + tok) * NST + (lane - DTRANK)] = v;
            } else {
                Cout[(t0 + tok) * NST + (lane - DTRANK - NST)] = v;
            }
        }
        {
            const int ridx = lane & 3;
            const int ks   = (lane >> 2) & 3;
            const int tsub = lane >> 4;
            const int r4   = 64 + ridx;
            const int tok  = wv * 4 + tsub;
            const float4* wr = (const float4*)(xproj_w + r4 * ED + ks * 32);
            const float4* yv = (const float4*)&xcs[tok][ks * 32];
            float4 a4 = make_float4(0.f, 0.f, 0.f, 0.f);
            #pragma unroll
            for (int i = 0; i < 8; ++i) {
                float4 hv = yv[i]; float4 wv4 = wr[i];
                a4.x = fmaf(hv.x, wv4.x, a4.x);
                a4.y = fmaf(hv.y, wv4.y, a4.y);
                a4.z = fmaf(hv.z, wv4.z, a4.z);
                a4.w = fmaf(hv.w, wv4.w, a4.w);
            }
            float v = hsum4(a4);
            v += __shfl_xor(v, 4, 64);
            v += __shfl_xor(v, 8, 64);
            if (ks == 0) Cout[(t0 + tok) * NST + (r4 - DTRANK - NST)] = v;
        }
    }
    __syncthreads();

    {   // dtproj + softplus -> dl (aliased LDS) + delta_out
        const float4 dwv = *(const float4*)(dtproj_w + e * DTRANK);
        const float bias = dtproj_b[e];
        #pragma unroll 2
        for (int j = 0; j < 8; ++j) {
            const int tok = half * 8 + j;
            float a = bias;
            a = fmaf(dts[tok][0], dwv.x, a);
            a = fmaf(dts[tok][1], dwv.y, a);
            a = fmaf(dts[tok][2], dwv.z, a);
            a = fmaf(dts[tok][3], dwv.w, a);
            const float sp = fmaxf(a, 0.f) + log1pf(__expf(-fabsf(a)));
            dl[tok][e] = sp;
            delta_out[(t0 + tok) * ED + e] = sp;
        }
    }
    __syncthreads();

    {   // local scan: two 8-state passes (unroll 2), Aen from hoisted regs
        float dsum = 0.f;
        #pragma unroll 4
        for (int l = 0; l < TT; ++l) dsum += dl[l][e];

        #pragma unroll 1
        for (int g = 0; g < 2; ++g) {
            const int n0 = half * 16 + g * 8;
            float Aen[8];
            #pragma unroll
            for (int k = 0; k < 8; ++k) Aen[k] = Aen16[g * 8 + k];
            float hs[8];
            #pragma unroll
            for (int k = 0; k < 8; ++k) hs[k] = 0.f;
            #pragma unroll 2
            for (int l = 0; l < TT; ++l) {
                const float de   = dl[l][e];
                const float dexc = de * xcs[l][e];
                const float4 B0 = *(const float4*)&Bs[l][n0];
                const float4 B1 = *(const float4*)&Bs[l][n0 + 4];
                float a;
                a = __expf(de * Aen[0]); hs[0] = fmaf(a, hs[0], B0.x * dexc);
                a = __expf(de * Aen[1]); hs[1] = fmaf(a, hs[1], B0.y * dexc);
                a = __expf(de * Aen[2]); hs[2] = fmaf(a, hs[2], B0.z * dexc);
                a = __expf(de * Aen[3]); hs[3] = fmaf(a, hs[3], B0.w * dexc);
                a = __expf(de * Aen[4]); hs[4] = fmaf(a, hs[4], B1.x * dexc);
                a = __expf(de * Aen[5]); hs[5] = fmaf(a, hs[5], B1.y * dexc);
                a = __expf(de * Aen[6]); hs[6] = fmaf(a, hs[6], B1.z * dexc);
                a = __expf(de * Aen[7]); hs[7] = fmaf(a, hs[7], B1.w * dexc);
            }
            const size_t idx = (((size_t)b * NC + c) * ED + e) * NST + n0;
            *(float4*)(hloc + idx)     = make_float4(hs[0], hs[1], hs[2], hs[3]);
            *(float4*)(hloc + idx + 4) = make_float4(hs[4], hs[5], hs[6], hs[7]);
            *(float4*)(aprod + idx) =
                make_float4(__expf(Aen[0] * dsum), __expf(Aen[1] * dsum),
                            __expf(Aen[2] * dsum), __expf(Aen[3] * dsum));
            *(float4*)(aprod + idx + 4) =
                make_float4(__expf(Aen[4] * dsum), __expf(Aen[5] * dsum),
                            __expf(Aen[6] * dsum), __expf(Aen[7] * dsum));
        }
    }
}

// ---------------- K3b: chunk combine. 256 blocks x 64 threads (1 wave/block) so
// the HBM/L2 stream spreads over all 256 CUs (was 64 blocks -> 64 CUs).
__global__ __launch_bounds__(64) void k_scan_combine(
    const float* __restrict__ aprod, float* __restrict__ hloc,
    float* __restrict__ hend)
{
    const int t = blockIdx.x * 64 + threadIdx.x;      // 0..16383
    const int b = t >> 12;                            // ED*NST = 4096
    const int en = t & 4095;
    size_t idx = (size_t)b * NC * (ED * NST) + en;
    float h = 0.f;
    #pragma unroll 4
    for (int c = 0; c < NC; ++c) {
        const float a = aprod[idx];
        const float u = hloc[idx];
        hloc[idx] = h;                 // initial state for chunk c
        h = fmaf(a, h, u);
        idx += ED * NST;
    }
    hend[(size_t)b * (ED * NST) + en] = h;
}

// ---------------- K_C (layers 1..3): scan(y in LDS) + outproj + residual + rms + inproj
__global__ __launch_bounds__(256) void k_scan_gemm(
    const float* __restrict__ delta, const float* __restrict__ Bv,
    const float* __restrict__ Cv, const float* __restrict__ xc,
    const float* __restrict__ zbin, const float* __restrict__ A_log,
    const float* __restrict__ Dp, const float* __restrict__ hinit,
    const float* __restrict__ ow, const float* __restrict__ ob,
    const float* __restrict__ hin, const float* __restrict__ norm_w,
    const float* __restrict__ in_w, const float* __restrict__ in_b,
    float* __restrict__ hout, float* __restrict__ xin, float* __restrict__ zb)
{
    const int blk = blockIdx.x;             // BSZ * NC = 512
    const int b   = blk >> 7;
    const int c   = blk & 127;
    const int l0  = c * TT;
    const size_t t0 = (size_t)b * Lseq + l0;
    const int tid = threadIdx.x;
    const int e = tid & 127, half = tid >> 7;

    __shared__ __align__(16) float dlS[TT][ED];
    __shared__ __align__(16) float xcS[TT][ED];
    __shared__ __align__(16) float BsS[TT][NST];
    __shared__ __align__(16) float CsS[TT][NST];
    __shared__ __align__(16) float ys[TT][ED];
    __shared__ __align__(16) float pp[2][TT][ED];
    __shared__ __align__(16) float hn[TT][DM];

    // ---- hoisted: Aen + hinit (overlap with staging) ----
    float Aen16[16];
    {
        const float4* a4 = (const float4*)(A_log + e * NST + half * 16);
        #pragma unroll
        for (int i = 0; i < 4; ++i) {
            float4 v = a4[i];
            Aen16[i*4+0] = -__expf(v.x); Aen16[i*4+1] = -__expf(v.y);
            Aen16[i*4+2] = -__expf(v.z); Aen16[i*4+3] = -__expf(v.w);
        }
    }

    {
        const float4* dsrc = (const float4*)(delta + t0 * ED);
        const float4* xsrc = (const float4*)(xc + t0 * ED);
        float4* ddst = (float4*)&dlS[0][0];
        float4* xdst = (float4*)&xcS[0][0];
        #pragma unroll
        for (int i = 0; i < 2; ++i) {
            ddst[tid + i * 256] = dsrc[tid + i * 256];
            xdst[tid + i * 256] = xsrc[tid + i * 256];
        }
        if (tid < 128) {
            ((float4*)&BsS[0][0])[tid] = ((const float4*)(Bv + t0 * NST))[tid];
            ((float4*)&CsS[0][0])[tid] = ((const float4*)(Cv + t0 * NST))[tid];
        }
    }
    __syncthreads();

    #pragma unroll 1
    for (int g = 0; g < 2; ++g) {
        const int n0 = half * 16 + g * 8;
        float Aen[8];
        #pragma unroll
        for (int k = 0; k < 8; ++k) Aen[k] = Aen16[g * 8 + k];
        float hs[8];
        {
            const size_t idx = (((size_t)b * NC + c) * ED + e) * NST + n0;
            const float4 h0 = *(const float4*)(hinit + idx);
            const float4 h1 = *(const float4*)(hinit + idx + 4);
            hs[0] = h0.x; hs[1] = h0.y; hs[2] = h0.z; hs[3] = h0.w;
            hs[4] = h1.x; hs[5] = h1.y; hs[6] = h1.z; hs[7] = h1.w;
        }
        #pragma unroll 2
        for (int l = 0; l < TT; ++l) {
            const float de   = dlS[l][e];
            const float dexc = de * xcS[l][e];
            const float4 B0 = *(const float4*)&BsS[l][n0];
            const float4 B1 = *(const float4*)&BsS[l][n0 + 4];
            const float4 C0 = *(const float4*)&CsS[l][n0];
            const float4 C1 = *(const float4*)&CsS[l][n0 + 4];
            float a, p = 0.f;
            a = __expf(de * Aen[0]); hs[0] = fmaf(a, hs[0], B0.x * dexc); p = fmaf(hs[0], C0.x, p);
            a = __expf(de * Aen[1]); hs[1] = fmaf(a, hs[1], B0.y * dexc); p = fmaf(hs[1], C0.y, p);
            a = __expf(de * Aen[2]); hs[2] = fmaf(a, hs[2], B0.z * dexc); p = fmaf(hs[2], C0.z, p);
            a = __expf(de * Aen[3]); hs[3] = fmaf(a, hs[3], B0.w * dexc); p = fmaf(hs[3], C0.w, p);
            a = __expf(de * Aen[4]); hs[4] = fmaf(a, hs[4], B1.x * dexc); p = fmaf(hs[4], C1.x, p);
            a = __expf(de * Aen[5]); hs[5] = fmaf(a, hs[5], B1.y * dexc); p = fmaf(hs[5], C1.y, p);
            a = __expf(de * Aen[6]); hs[6] = fmaf(a, hs[6], B1.z * dexc); p = fmaf(hs[6], C1.z, p);
            a = __expf(de * Aen[7]); hs[7] = fmaf(a, hs[7], B1.w * dexc); p = fmaf(hs[7], C1.w, p);
            if (g == 0) pp[half][l][e] = p;
            else        pp[half][l][e] += p;
        }
    }
    __syncthreads();
    {
        const float dpe = Dp[e];
        #pragma unroll 2
        for (int j = 0; j < 8; ++j) {
            const int tl = half * 8 + j;
            const size_t tok = t0 + tl;
            const float p = pp[0][tl][e] + pp[1][tl][e];
            const float zi = zbin[tok * ED + e];
            ys[tl][e] = (p + dpe * xcS[tl][e]) * (zi * sigf(zi));
        }
    }
    __syncthreads();

    const int lane = tid & 63;
    const int wv = tid >> 6;
    const float nw = norm_w[lane];
    float hval[4];
    {
        float4 acc[4];
        #pragma unroll
        for (int j = 0; j < 4; ++j) acc[j] = make_float4(0.f, 0.f, 0.f, 0.f);
        #pragma unroll 1
        for (int p = 0; p < 4; ++p) {
            float4 w4[8];
            const float4* wr = (const float4*)(ow + lane * ED + p * 32);
            #pragma unroll
            for (int q = 0; q < 8; ++q) w4[q] = wr[q];
            #pragma unroll
            for (int j = 0; j < 4; ++j) {
                const float4* yv = (const float4*)&ys[wv * 4 + j][p * 32];
                #pragma unroll
                for (int q = 0; q < 8; ++q) {
                    float4 hv = yv[q];
                    acc[j].x = fmaf(hv.x, w4[q].x, acc[j].x);
                    acc[j].y = fmaf(hv.y, w4[q].y, acc[j].y);
                    acc[j].z = fmaf(hv.z, w4[q].z, acc[j].z);
                    acc[j].w = fmaf(hv.w, w4[q].w, acc[j].w);
                }
            }
        }
        const float obd = ob[lane];
        #pragma unroll
        for (int j = 0; j < 4; ++j) {
            const size_t tok = t0 + wv * 4 + j;
            hval[j] = hsum4(acc[j]) + obd + hin[tok * DM + lane];
            hout[tok * DM + lane] = hval[j];
        }
    }
    #pragma unroll
    for (int j = 0; j < 4; ++j) {
        float ss = hval[j] * hval[j];
        #pragma unroll
        for (int off = 32; off; off >>= 1) ss += __shfl_xor(ss, off, 64);
        const float sc = rsqrtf(ss * (1.0f / DM) + EPSV);
        hn[wv * 4 + j][lane] = hval[j] * sc * nw;
    }
    __syncthreads();
    inproj16(in_w, in_b, (const float (*)[DM])hn, xin, zb, t0, tid);
}

// ---------------- K5: last layer head: y(L-1) from hend, then fc dot -> logits
__global__ __launch_bounds__(128) void k_final_last(
    const float* __restrict__ hend, const float* __restrict__ Cv,
    const float* __restrict__ xc, const float* __restrict__ zb,
    const float* __restrict__ Dp, const float* __restrict__ fcw,
    const float* __restrict__ fcb, float* __restrict__ out)
{
    const int b = blockIdx.x;
    const int e = threadIdx.x;
    const size_t tok = (size_t)b * Lseq + (Lseq - 1);
    const float* hp = hend + (size_t)b * (ED * NST) + e * NST;
    const float* cp = Cv + tok * NST;
    float p = 0.f;
    #pragma unroll
    for (int n = 0; n < NST; ++n) p = fmaf(hp[n], cp[n], p);
    const float xce = xc[tok * ED + e];
    const float zi  = zb[tok * ED + e];
    float val = (p + Dp[e] * xce) * (zi * sigf(zi)) * fcw[e];
    __shared__ float sred[2];
    #pragma unroll
    for (int off = 32; off; off >>= 1) val += __shfl_xor(val, off, 64);
    if ((threadIdx.x & 63) == 0) sred[threadIdx.x >> 6] = val;
    __syncthreads();
    if (threadIdx.x == 0) out[b] = sred[0] + sred[1] + fcb[0];
}

extern "C" void kernel_launch(void* const* d_in, const int* in_sizes, int n_in,
                              void* d_out, int out_size, void* d_ws, size_t ws_size,
                              hipStream_t stream)
{
    const float* x         = (const float*)d_in[0];
    const float* in_w      = (const float*)d_in[1];
    const float* in_b      = (const float*)d_in[2];
    const float* conv_w    = (const float*)d_in[3];
    const float* conv_b    = (const float*)d_in[4];
    const float* xproj_w   = (const float*)d_in[5];
    const float* dtproj_w  = (const float*)d_in[6];
    const float* dtproj_b  = (const float*)d_in[7];
    const float* A_log     = (const float*)d_in[8];
    const float* Dp        = (const float*)d_in[9];
    const float* outproj_w = (const float*)d_in[10];
    const float* outproj_b = (const float*)d_in[11];
    const float* norm_w    = (const float*)d_in[12];
    const float* fc_w      = (const float*)d_in[13];
    const float* fc_b      = (const float*)d_in[14];

    const size_t TOK = (size_t)BSZ * Lseq;
    float* ws = (float*)d_ws;
    float* h0    = ws; ws += TOK * DM;
    float* h1    = ws; ws += TOK * DM;
    float* xin   = ws; ws += TOK * ED;
    float* zbuf  = ws; ws += TOK * ED;
    float* xc    = ws; ws += TOK * ED;
    float* dlt   = ws; ws += TOK * ED;
    float* Bv    = ws; ws += TOK * NST;
    float* Cv    = ws; ws += TOK * NST;
    float* aprod = ws; ws += (size_t)BSZ * NC * ED * NST;   // 8 MB
    float* hloc  = ws; ws += (size_t)BSZ * NC * ED * NST;   // 8 MB, becomes hinit
    float* hend  = ws; ws += (size_t)BSZ * ED * NST;

    const float* hres = x;
    float* hbufs[2] = { h0, h1 };

    k_layer_gemm<<<(int)(TOK / TT), 256, 0, stream>>>(
        x, norm_w, in_w, in_b, xin, zbuf);

    for (int i = 0; i < NLAYERS; ++i) {
        const int last = (i == NLAYERS - 1);
        const float* Alog_i = A_log + (size_t)i * ED * NST;
        k_conv_scan<<<(int)(BSZ * NC), 256, 0, stream>>>(
            xin, conv_w + (size_t)i * ED * DCONVK, conv_b + (size_t)i * ED,
            xproj_w + (size_t)i * (DTRANK + 2 * NST) * ED,
            dtproj_w + (size_t)i * ED * DTRANK, dtproj_b + (size_t)i * ED,
            Alog_i, xc, dlt, Bv, Cv, aprod, hloc);
        k_scan_combine<<<(BSZ * ED * NST) / 64, 64, 0, stream>>>(
            aprod, hloc, hend);
        if (!last) {
            float* hout = hbufs[i & 1];
            k_scan_gemm<<<(int)(BSZ * NC), 256, 0, stream>>>(
                dlt, Bv, Cv, xc, zbuf, Alog_i, Dp + (size_t)i * ED, hloc,
                outproj_w + (size_t)i * DM * ED, outproj_b + (size_t)i * DM,
                hres, norm_w + (size_t)(i + 1) * DM,
                in_w + (size_t)(i + 1) * 2 * ED * DM,
                in_b + (size_t)(i + 1) * 2 * ED,
                hout, xin, zbuf);
            hres = hout;
        } else {
            k_final_last<<<BSZ, 128, 0, stream>>>(
                hend, Cv, xc, zbuf, Dp + (size_t)i * ED, fc_w, fc_b, (float*)d_out);
        }
    }
}